// Round 5
// baseline (388.846 us; speedup 1.0000x reference)
//
#include <hip/hip_runtime.h>
#include <stdint.h>

typedef unsigned long long u64;
typedef unsigned int u32;
typedef float f32x4 __attribute__((ext_vector_type(4)));   // clang vector: nontemporal-builtin OK
typedef u64 u64x2 __attribute__((ext_vector_type(2)));

#define HW 65536   // 256*256
#define WD 256

// ---------------------------------------------------------------------------
// Kernel 1: pack weights. 64 blocks (one per o), 64 lanes (one per i).
// pw[o][k] bit i = signbit(w[o][i][kh][kw]) -- built with __ballot (bit=lane).
// scale[o] = mean|w[o]| via wave shuffle reduction.
// ---------------------------------------------------------------------------
__global__ __launch_bounds__(64) void pack_w_kernel(const float* __restrict__ wt,
                                                    u64* __restrict__ pw,
                                                    float* __restrict__ scale) {
    const int o = blockIdx.x;
    const int i = threadIdx.x;          // lane == input channel == bit index
    const float* p = wt + o * 576 + i * 9;
    float v[9];
    float s = 0.f;
#pragma unroll
    for (int k = 0; k < 9; k++) { v[k] = p[k]; s += fabsf(v[k]); }
#pragma unroll
    for (int k = 0; k < 9; k++) {
        u64 m = __ballot((__float_as_uint(v[k]) >> 31) != 0u);
        if (i == 0) pw[o * 9 + k] = m;
    }
#pragma unroll
    for (int off = 32; off > 0; off >>= 1) s += __shfl_down(s, off);
    if (i == 0) scale[o] = s * (1.0f / 576.0f);
}

// ---------------------------------------------------------------------------
// Kernel 2: pack activations WITH the temporal channel shift folded in.
// y[n=(b,t)][c] = x[b*3+(t+2)%3][32+c]  for c in [0,32)  -> bits 0..31
//              = x[n][c-32]             for c in [32,64) -> bits 32..63
// ---------------------------------------------------------------------------
__global__ __launch_bounds__(256) void pack_x_kernel(const float* __restrict__ x,
                                                     u64* __restrict__ px) {
    const int n = blockIdx.x >> 6;                                // frame 0..11
    const int s = ((blockIdx.x & 63) << 10) + (threadIdx.x << 2); // spatial pos, 4/thread
    const int b = n / 3;
    const int t = n - b * 3;
    const int fp = b * 3 + (t + 2) % 3;                           // source frame for low bits

    const f32x4* xa = (const f32x4*)(x + ((size_t)fp * 64 + 32) * HW + s);
    const f32x4* xb = (const f32x4*)(x + (size_t)n * 64 * HW + s);

    u32 lo0 = 0, lo1 = 0, lo2 = 0, lo3 = 0;
    u32 hi0 = 0, hi1 = 0, hi2 = 0, hi3 = 0;
#pragma unroll
    for (int c = 0; c < 32; c++) {
        f32x4 va = __builtin_nontemporal_load(xa + c * (HW / 4));
        lo0 |= (__float_as_uint(va.x) >> 31) << c;
        lo1 |= (__float_as_uint(va.y) >> 31) << c;
        lo2 |= (__float_as_uint(va.z) >> 31) << c;
        lo3 |= (__float_as_uint(va.w) >> 31) << c;
        f32x4 vb = __builtin_nontemporal_load(xb + c * (HW / 4));
        hi0 |= (__float_as_uint(vb.x) >> 31) << c;
        hi1 |= (__float_as_uint(vb.y) >> 31) << c;
        hi2 |= (__float_as_uint(vb.z) >> 31) << c;
        hi3 |= (__float_as_uint(vb.w) >> 31) << c;
    }
    u64* dst = px + (size_t)n * HW + s;          // 32B aligned (s % 4 == 0)
    u64x2 d01 = { ((u64)hi0 << 32) | lo0, ((u64)hi1 << 32) | lo1 };
    u64x2 d23 = { ((u64)hi2 << 32) | lo2, ((u64)hi3 << 32) | lo3 };
    *(u64x2*)(dst)     = d01;
    *(u64x2*)(dst + 2) = d23;
}

// ---------------------------------------------------------------------------
// Kernel 3: binary conv, INTERIOR-CORRECT fast path. 4 w-positions per thread,
// one float4 nontemporal store per o. NO masking: preload uses clamped
// addresses (always in-bounds); border pixels (h or w in {0,255}) get wrong
// values and are overwritten by bconv_edge_kernel afterwards. The halo word
// W[r][0]/W[r][5] only feeds position j=0/j=3, which at the picture edge IS a
// border pixel -- interior results never consume clamped garbage.
// ---------------------------------------------------------------------------
__global__ __launch_bounds__(256) void bconv_kernel(const u64* __restrict__ px,
                                                    const u64* __restrict__ pw,
                                                    const float* __restrict__ scale,
                                                    float* __restrict__ out) {
    const int g  = threadIdx.x & 63;        // w-group
    const int w4 = g << 2;                  // first w of this thread
    const int h  = (blockIdx.x << 2) + (threadIdx.x >> 6);
    const int n  = blockIdx.y;
    const u64* base = px + (size_t)n * HW;

    // preload 3 rows x 6 words (taps for 4 positions), clamped addresses
    u64 W[3][6];
#pragma unroll
    for (int r = 0; r < 3; r++) {
        const int hh = min(max(h - 1 + r, 0), 255);
        const u64* row = base + hh * WD;
        W[r][0] = row[max(w4 - 1, 0)];              // left halo (only j=0 uses it)
#pragma unroll
        for (int k = 1; k < 5; k++) W[r][k] = row[w4 - 1 + k];
        W[r][5] = row[min(w4 + 4, 255)];            // right halo (only j=3 uses it)
    }

    float* op = out + (size_t)n * 64 * HW + h * WD + w4;     // 16B aligned

#pragma unroll 4
    for (int o = 0; o < 64; o++) {
        const u64* wp = pw + o * 9;         // wave-uniform -> scalar loads
        int c0 = 0, c1 = 0, c2 = 0, c3 = 0;
#pragma unroll
        for (int r = 0; r < 3; r++) {
#pragma unroll
            for (int dw = 0; dw < 3; dw++) {
                const u64 t = wp[r * 3 + dw];
                c0 += __popcll(W[r][0 + dw] ^ t);
                c1 += __popcll(W[r][1 + dw] ^ t);
                c2 += __popcll(W[r][2 + dw] ^ t);
                c3 += __popcll(W[r][3 + dw] ^ t);
            }
        }
        const float sc = scale[o];
        const float b  = 576.f * sc, m = -2.f * sc;
        f32x4 v = { fmaf(m, (float)c0, b), fmaf(m, (float)c1, b),
                    fmaf(m, (float)c2, b), fmaf(m, (float)c3, b) };
        __builtin_nontemporal_store(v, (f32x4*)(op + (size_t)o * HW));
    }
}

// ---------------------------------------------------------------------------
// Kernel 4: border fixup. Recomputes the 1020 border pixels per frame with the
// proven R2 masked path (mask applied to XOR result + 32/OOB-tap correction).
// 8 threads per pixel, 8 o-channels each. Per frame: 1024 pixel-slots x 8 =
// 8192 threads = 32 blocks. Runs after bconv_kernel on the same stream.
// ---------------------------------------------------------------------------
__global__ __launch_bounds__(256) void bconv_edge_kernel(const u64* __restrict__ px,
                                                         const u64* __restrict__ pw,
                                                         const float* __restrict__ scale,
                                                         float* __restrict__ out) {
    const int idx = (blockIdx.x << 8) + threadIdx.x;   // 0..8191 within frame
    const int p   = idx >> 3;                          // pixel slot 0..1023
    const int og  = (idx & 7) << 3;                    // first o of this thread
    const int n   = blockIdx.y;
    if (p >= 1020) return;

    int h, w;
    if (p < 256)      { h = 0;       w = p;       }
    else if (p < 512) { h = 255;     w = p - 256; }
    else if (p < 766) { w = 0;       h = p - 511; }    // h = 1..254
    else              { w = 255;     h = p - 765; }    // h = 1..254

    const u64* base = px + (size_t)n * HW;
    u64 xv[9];
    u64 mk[9];
    int ninv = 0;
#pragma unroll
    for (int dh = -1; dh <= 1; dh++) {
#pragma unroll
        for (int dw = -1; dw <= 1; dw++) {
            const int k = (dh + 1) * 3 + (dw + 1);
            const int hh = h + dh, ww = w + dw;
            const bool valid = (hh >= 0) && (hh < 256) && (ww >= 0) && (ww < 256);
            xv[k] = base[min(max(hh, 0), 255) * WD + min(max(ww, 0), 255)];
            mk[k] = valid ? ~0ull : 0ull;   // mask kills OOB contribution
            ninv += valid ? 0 : 1;
        }
    }
    const int basecnt = 32 * ninv;          // each OOB tap contributes exactly 0

    float* op = out + (size_t)n * 64 * HW + h * WD + w;
#pragma unroll
    for (int j = 0; j < 8; j++) {
        const int o = og + j;
        const u64* wp = pw + o * 9;
        int cnt = basecnt;
#pragma unroll
        for (int k = 0; k < 9; k++) cnt += __popcll((xv[k] ^ wp[k]) & mk[k]);
        const float sc = scale[o];
        op[(size_t)o * HW] = fmaf(-2.f * sc, (float)cnt, 576.f * sc);
    }
}

// ---------------------------------------------------------------------------
extern "C" void kernel_launch(void* const* d_in, const int* in_sizes, int n_in,
                              void* d_out, int out_size, void* d_ws, size_t ws_size,
                              hipStream_t stream) {
    (void)in_sizes; (void)n_in; (void)out_size; (void)ws_size;
    const float* x  = (const float*)d_in[0];
    const float* wt = (const float*)d_in[1];
    float* out = (float*)d_out;

    // workspace layout: px (12*65536 u64 = 6.0 MiB) | pw (576 u64) | scale (64 f32)
    u64* px = (u64*)d_ws;
    u64* pw = px + (size_t)12 * HW;
    float* scale = (float*)(pw + 576);

    pack_w_kernel<<<64, 64, 0, stream>>>(wt, pw, scale);
    pack_x_kernel<<<768, 256, 0, stream>>>(x, px);
    bconv_kernel<<<dim3(64, 12), 256, 0, stream>>>(px, pw, scale, out);
    bconv_edge_kernel<<<dim3(32, 12), 256, 0, stream>>>(px, pw, scale, out);
}